// Round 1
// baseline (545.499 us; speedup 1.0000x reference)
//
#include <hip/hip_runtime.h>
#include <stdint.h>
#include <stddef.h>

#define NN 64
#define BB 128
#define LL 4096
#define EE 16

typedef __attribute__((ext_vector_type(4))) float f32x4;
typedef __attribute__((ext_vector_type(8))) short short8;
typedef __attribute__((ext_vector_type(4))) unsigned short u16x4;

__device__ __forceinline__ unsigned short f2bf(float f) {
  union { float f; unsigned u; } v; v.f = f;
  unsigned r = v.u + 0x7FFFu + ((v.u >> 16) & 1u);   // RNE
  return (unsigned short)(r >> 16);
}
__device__ __forceinline__ float bf2f(unsigned short h) {
  union { unsigned u; float f; } v; v.u = ((unsigned)h) << 16;
  return v.f;
}
__device__ __forceinline__ void gload16(const void* g, void* l) {
  __builtin_amdgcn_global_load_lds((const __attribute__((address_space(1))) void*)g,
                                   (__attribute__((address_space(3))) void*)l,
                                   16, 0, 0);
}

// ---------------- K1: fp32 -> bf16 convert (Wm) ----------------
__global__ __launch_bounds__(256) void k_cvt(const float* __restrict__ src,
                                             unsigned short* __restrict__ dst, int n4) {
  int i = blockIdx.x * 256 + threadIdx.x;
  int stride = gridDim.x * 256;
  for (; i < n4; i += stride) {
    f32x4 v = ((const f32x4*)src)[i];
    u16x4 o;
    o[0] = f2bf(v[0]); o[1] = f2bf(v[1]); o[2] = f2bf(v[2]); o[3] = f2bf(v[3]);
    ((u16x4*)dst)[i] = o;
  }
}

// ---------------- K2: att projections + feat->bf16 ----------------
// block: 256 thr, 8 rows of feat. Lane: row = lane>>3, eg = lane&7 (4 e-values),
// wave = k-slice. Weights chunk [128][36] (padded), feat chunk [8][132] (padded).
__global__ __launch_bounds__(256) void k_att(const float* __restrict__ feat,
    const float* __restrict__ Wl, const float* __restrict__ bl,
    const float* __restrict__ Wr, const float* __restrict__ br,
    unsigned short* __restrict__ feat_bf,
    float* __restrict__ att_l, float* __restrict__ att_r) {
  __shared__ __align__(16) float wlds[128][36];
  __shared__ __align__(16) float flds[8][132];
  __shared__ __align__(16) float red[4][64][4];
  int t = threadIdx.x;
  int rowBase = blockIdx.x * 8;
  int lane = t & 63, wave = t >> 6;
  int row = lane >> 3, eg = lane & 7;
  float acc0 = 0.f, acc1 = 0.f, acc2 = 0.f, acc3 = 0.f;
  for (int kc = 0; kc < 32; ++kc) {
    int k0 = kc * 128;
    __syncthreads();
    // stage weights: Wl -> cols 0..15, Wr -> cols 16..31
    for (int i = t; i < 512; i += 256) {
      int kk = i >> 2, ee = (i & 3) * 4;
      *(f32x4*)&wlds[kk][ee]      = *(const f32x4*)&Wl[(size_t)(k0 + kk) * 16 + ee];
      *(f32x4*)&wlds[kk][16 + ee] = *(const f32x4*)&Wr[(size_t)(k0 + kk) * 16 + ee];
    }
    // stage feat chunk + write bf16 copy
    {
      int rr = t >> 5, kk = (t & 31) * 4;
      size_t gi = (size_t)(rowBase + rr) * LL + k0 + kk;
      f32x4 v = *(const f32x4*)&feat[gi];
      *(f32x4*)&flds[rr][kk] = v;
      u16x4 o; o[0] = f2bf(v[0]); o[1] = f2bf(v[1]); o[2] = f2bf(v[2]); o[3] = f2bf(v[3]);
      *(u16x4*)&feat_bf[gi] = o;
    }
    __syncthreads();
    int kb = wave * 32;
    #pragma unroll
    for (int k2 = 0; k2 < 32; ++k2) {
      int k = kb + k2;
      float fv = flds[row][k];
      f32x4 wv = *(const f32x4*)&wlds[k][eg * 4];
      acc0 += fv * wv[0]; acc1 += fv * wv[1]; acc2 += fv * wv[2]; acc3 += fv * wv[3];
    }
  }
  red[wave][lane][0] = acc0; red[wave][lane][1] = acc1;
  red[wave][lane][2] = acc2; red[wave][lane][3] = acc3;
  __syncthreads();
  if (t < 64) {
    f32x4 s = *(f32x4*)&red[0][t][0];
    #pragma unroll
    for (int w2 = 1; w2 < 4; ++w2) {
      f32x4 v = *(f32x4*)&red[w2][t][0];
      s[0] += v[0]; s[1] += v[1]; s[2] += v[2]; s[3] += v[3];
    }
    int r = rowBase + (t >> 3);
    int e0 = (t & 7) * 4;
    #pragma unroll
    for (int q = 0; q < 4; ++q) {
      int e = e0 + q;
      if (e < 16) att_l[(size_t)r * 16 + e]        = s[q] + bl[e];
      else        att_r[(size_t)r * 16 + (e - 16)] = s[q] + br[e - 16];
    }
  }
}

// ---------------- K3: edge scores + BN + softmax ----------------
// one block per destination node d. e[s][b] in LDS; BN over b per (d,s);
// softmax over s per (d,b); writes w transposed: w_t[b][d][s].
__global__ __launch_bounds__(256) void k_edge(const float* __restrict__ att_l,
    const float* __restrict__ att_r, const float* __restrict__ gamma,
    const float* __restrict__ beta, float* __restrict__ w_t) {
  __shared__ __align__(16) float attr[BB][20];
  __shared__ float el[NN][BB + 1];
  __shared__ float part[NN][4][2];
  __shared__ float sc[NN], sh[NN];
  int d = blockIdx.x, t = threadIdx.x;
  for (int i = t; i < 512; i += 256) {
    int b = i >> 2, e = (i & 3) * 4;
    *(f32x4*)&attr[b][e] = *(const f32x4*)&att_r[((size_t)d * BB + b) * 16 + e];
  }
  __syncthreads();
  for (int v = t; v < NN * BB; v += 256) {
    int s = v >> 7, b = v & 127;
    const float* al = &att_l[((size_t)s * BB + b) * 16];
    float acc = 0.f;
    #pragma unroll
    for (int e4 = 0; e4 < 4; ++e4) {
      f32x4 a = *(const f32x4*)&al[e4 * 4];
      f32x4 r = *(const f32x4*)&attr[b][e4 * 4];
      acc += a[0] * r[0] + a[1] * r[1] + a[2] * r[2] + a[3] * r[3];
    }
    el[s][b] = acc;
  }
  __syncthreads();
  {
    int s = t >> 2, q = t & 3;
    float sum = 0.f, ss = 0.f;
    for (int b = q * 32; b < q * 32 + 32; ++b) { float x = el[s][b]; sum += x; ss += x * x; }
    part[s][q][0] = sum; part[s][q][1] = ss;
  }
  __syncthreads();
  if (t < 64) {
    float sum = 0.f, ss = 0.f;
    #pragma unroll
    for (int q = 0; q < 4; ++q) { sum += part[t][q][0]; ss += part[t][q][1]; }
    float mu = sum * (1.f / 128.f);
    float var = ss * (1.f / 128.f) - mu * mu;
    int c = d * 64 + t;
    float a = gamma[c] * rsqrtf(fmaxf(var, 0.f) + 1e-5f);
    sc[t] = a; sh[t] = beta[c] - mu * a;
  }
  __syncthreads();
  if (t < 128) {
    int b = t;
    float y[64];
    float m = -1e30f;
    #pragma unroll
    for (int s = 0; s < 64; ++s) { y[s] = sc[s] * el[s][b] + sh[s]; m = fmaxf(m, y[s]); }
    float sum = 0.f;
    #pragma unroll
    for (int s = 0; s < 64; ++s) { y[s] = __expf(y[s] - m); sum += y[s]; }
    float inv = 1.f / sum;
    float* wp = &w_t[((size_t)b * 64 + d) * 64];
    #pragma unroll
    for (int s4 = 0; s4 < 16; ++s4) {
      f32x4 o;
      o[0] = y[s4 * 4 + 0] * inv; o[1] = y[s4 * 4 + 1] * inv;
      o[2] = y[s4 * 4 + 2] * inv; o[3] = y[s4 * 4 + 3] * inv;
      *(f32x4*)&wp[s4 * 4] = o;
    }
  }
}

// ---------------- K4: bf16 MFMA GEMM  out = relu(feat @ Wm^T + bm) ----------------
// m97 structure: 128x128 tile, BK=32, 4 waves (2x2 of 64x64), global_load_lds w=16,
// 16x mfma_f32_16x16x32_bf16 per K-step, bf16 epilogue store.
__global__ __launch_bounds__(256) void k_gemm(const unsigned short* __restrict__ A,
    const unsigned short* __restrict__ Bm, const float* __restrict__ bm,
    unsigned short* __restrict__ C) {
  __shared__ __align__(16) unsigned short As[128 * 32];
  __shared__ __align__(16) unsigned short Bs[128 * 32];
  int t = threadIdx.x;
  int bid = blockIdx.x;
  int tM = bid >> 5, tN = bid & 31;
  size_t rowBase = (size_t)tM * 128, colBase = (size_t)tN * 128;
  int lane = t & 63, wave = t >> 6;
  int wm = wave >> 1, wn = wave & 1;
  int srow = t >> 2, scol = (t & 3) * 8;
  const unsigned short* aP = A + (rowBase + srow) * LL + scol;
  const unsigned short* bP = Bm + (colBase + srow) * LL + scol;
  unsigned short* asD0 = As + t * 8;
  unsigned short* asD1 = As + 2048 + t * 8;
  unsigned short* bsD0 = Bs + t * 8;
  unsigned short* bsD1 = Bs + 2048 + t * 8;
  f32x4 acc[4][4] = {};
  int fro = lane & 15, fko = (lane >> 4) * 8;
  int aOff = (wm * 64 + fro) * 32 + fko;
  int bOff = (wn * 64 + fro) * 32 + fko;
  for (int kt = 0; kt < 128; ++kt) {
    int k0 = kt * 32;
    gload16(aP + k0, asD0);
    gload16(aP + (size_t)64 * LL + k0, asD1);
    gload16(bP + k0, bsD0);
    gload16(bP + (size_t)64 * LL + k0, bsD1);
    __syncthreads();
    short8 af[4], bf[4];
    #pragma unroll
    for (int mi = 0; mi < 4; ++mi) af[mi] = *(const short8*)&As[aOff + mi * 16 * 32];
    #pragma unroll
    for (int ni = 0; ni < 4; ++ni) bf[ni] = *(const short8*)&Bs[bOff + ni * 16 * 32];
    #pragma unroll
    for (int mi = 0; mi < 4; ++mi) {
      #pragma unroll
      for (int ni = 0; ni < 4; ++ni)
        acc[mi][ni] = __builtin_amdgcn_mfma_f32_16x16x32_bf16(af[mi], bf[ni], acc[mi][ni], 0, 0, 0);
    }
    __syncthreads();
  }
  int ro = (lane >> 4) * 4, co = lane & 15;
  #pragma unroll
  for (int ni = 0; ni < 4; ++ni) {
    size_t c = colBase + wn * 64 + ni * 16 + co;
    float bc = bm[c];
    #pragma unroll
    for (int mi = 0; mi < 4; ++mi) {
      size_t r0 = rowBase + wm * 64 + mi * 16 + ro;
      #pragma unroll
      for (int j = 0; j < 4; ++j) {
        float v = acc[mi][ni][j] + bc;
        v = fmaxf(v, 0.f);
        C[(r0 + j) * LL + c] = f2bf(v);
      }
    }
  }
}

// ---------------- K5: rst[d,b,l] = sum_s w[d,s,b]*out[s,b,l] + bias[l] ----------------
__global__ __launch_bounds__(256) void k_agg(const float* __restrict__ w_t,
    const unsigned short* __restrict__ outb, const float* __restrict__ bias,
    float* __restrict__ rst) {
  __shared__ __align__(16) float wl[64][64];
  int b = blockIdx.y;
  int t = threadIdx.x;
  int l = blockIdx.x * 256 + t;
  {
    const f32x4* src = (const f32x4*)&w_t[(size_t)b * 4096];
    f32x4* dstp = (f32x4*)&wl[0][0];
    for (int i = t; i < 1024; i += 256) dstp[i] = src[i];
  }
  __syncthreads();
  float o[64];
  #pragma unroll
  for (int s = 0; s < 64; ++s) o[s] = bf2f(outb[((size_t)s * BB + b) * LL + l]);
  float bs = bias[l];
  #pragma unroll 2
  for (int d = 0; d < 64; ++d) {
    float acc = 0.f;
    #pragma unroll
    for (int s4 = 0; s4 < 16; ++s4) {
      f32x4 wv = *(const f32x4*)&wl[d][s4 * 4];
      acc += wv[0] * o[s4 * 4 + 0] + wv[1] * o[s4 * 4 + 1]
           + wv[2] * o[s4 * 4 + 2] + wv[3] * o[s4 * 4 + 3];
    }
    rst[((size_t)d * BB + b) * LL + l] = acc + bs;
  }
}

extern "C" void kernel_launch(void* const* d_in, const int* in_sizes, int n_in,
                              void* d_out, int out_size, void* d_ws, size_t ws_size,
                              hipStream_t stream) {
  (void)in_sizes; (void)n_in; (void)out_size; (void)ws_size;
  const float* feat  = (const float*)d_in[0];
  const float* Wl    = (const float*)d_in[1];
  const float* bl    = (const float*)d_in[2];
  const float* Wr    = (const float*)d_in[3];
  const float* br    = (const float*)d_in[4];
  const float* Wm    = (const float*)d_in[5];
  const float* bm    = (const float*)d_in[6];
  const float* gamma = (const float*)d_in[7];
  const float* beta  = (const float*)d_in[8];
  const float* bias  = (const float*)d_in[9];
  char* ws = (char*)d_ws;
  // workspace layout (bytes)
  unsigned short* feat_bf = (unsigned short*)(ws);                 // 67,108,864
  unsigned short* wm_bf   = (unsigned short*)(ws + 67108864ull);   // 33,554,432
  unsigned short* out_bf  = (unsigned short*)(ws + 100663296ull);  // 67,108,864
  float* att_l = (float*)(ws + 167772160ull);                      //    524,288
  float* att_r = (float*)(ws + 168296448ull);                      //    524,288
  float* w_t   = (float*)(ws + 168820736ull);                      //  2,097,152
  float* rst = (float*)d_out;

  k_cvt<<<dim3(2048), dim3(256), 0, stream>>>(Wm, wm_bf, (LL * LL) / 4);
  k_att<<<dim3(1024), dim3(256), 0, stream>>>(feat, Wl, bl, Wr, br, feat_bf, att_l, att_r);
  k_edge<<<dim3(64), dim3(256), 0, stream>>>(att_l, att_r, gamma, beta, w_t);
  k_gemm<<<dim3(2048), dim3(256), 0, stream>>>(feat_bf, wm_bf, bm, out_bf);
  k_agg<<<dim3(16, 128), dim3(256), 0, stream>>>(w_t, out_bf, bias, rst);
}

// Round 2
// 442.243 us; speedup vs baseline: 1.2335x; 1.2335x over previous
//
#include <hip/hip_runtime.h>
#include <stdint.h>
#include <stddef.h>

#define NN 64
#define BB 128
#define LL 4096
#define EE 16

typedef __attribute__((ext_vector_type(4))) float f32x4;
typedef __attribute__((ext_vector_type(8))) short short8;
typedef __attribute__((ext_vector_type(4))) unsigned short u16x4;

__device__ __forceinline__ unsigned short f2bf(float f) {
  union { float f; unsigned u; } v; v.f = f;
  unsigned r = v.u + 0x7FFFu + ((v.u >> 16) & 1u);   // RNE
  return (unsigned short)(r >> 16);
}
__device__ __forceinline__ float bf2f(unsigned short h) {
  union { unsigned u; float f; } v; v.u = ((unsigned)h) << 16;
  return v.f;
}
__device__ __forceinline__ void gload16(const void* g, void* l) {
  __builtin_amdgcn_global_load_lds((const __attribute__((address_space(1))) void*)g,
                                   (__attribute__((address_space(3))) void*)l,
                                   16, 0, 0);
}

// ---------------- K1: fp32 -> bf16 convert (Wm) ----------------
__global__ __launch_bounds__(256) void k_cvt(const float* __restrict__ src,
                                             unsigned short* __restrict__ dst, int n4) {
  int i = blockIdx.x * 256 + threadIdx.x;
  int stride = gridDim.x * 256;
  for (; i < n4; i += stride) {
    f32x4 v = ((const f32x4*)src)[i];
    u16x4 o;
    o[0] = f2bf(v[0]); o[1] = f2bf(v[1]); o[2] = f2bf(v[2]); o[3] = f2bf(v[3]);
    ((u16x4*)dst)[i] = o;
  }
}

// ---------------- K2: att projections + feat->bf16 ----------------
__global__ __launch_bounds__(256) void k_att(const float* __restrict__ feat,
    const float* __restrict__ Wl, const float* __restrict__ bl,
    const float* __restrict__ Wr, const float* __restrict__ br,
    unsigned short* __restrict__ feat_bf,
    float* __restrict__ att_l, float* __restrict__ att_r) {
  __shared__ __align__(16) float wlds[128][36];
  __shared__ __align__(16) float flds[8][132];
  __shared__ __align__(16) float red[4][64][4];
  int t = threadIdx.x;
  int rowBase = blockIdx.x * 8;
  int lane = t & 63, wave = t >> 6;
  int row = lane >> 3, eg = lane & 7;
  float acc0 = 0.f, acc1 = 0.f, acc2 = 0.f, acc3 = 0.f;
  for (int kc = 0; kc < 32; ++kc) {
    int k0 = kc * 128;
    __syncthreads();
    for (int i = t; i < 512; i += 256) {
      int kk = i >> 2, ee = (i & 3) * 4;
      *(f32x4*)&wlds[kk][ee]      = *(const f32x4*)&Wl[(size_t)(k0 + kk) * 16 + ee];
      *(f32x4*)&wlds[kk][16 + ee] = *(const f32x4*)&Wr[(size_t)(k0 + kk) * 16 + ee];
    }
    {
      int rr = t >> 5, kk = (t & 31) * 4;
      size_t gi = (size_t)(rowBase + rr) * LL + k0 + kk;
      f32x4 v = *(const f32x4*)&feat[gi];
      *(f32x4*)&flds[rr][kk] = v;
      u16x4 o; o[0] = f2bf(v[0]); o[1] = f2bf(v[1]); o[2] = f2bf(v[2]); o[3] = f2bf(v[3]);
      *(u16x4*)&feat_bf[gi] = o;
    }
    __syncthreads();
    int kb = wave * 32;
    #pragma unroll
    for (int k2 = 0; k2 < 32; ++k2) {
      int k = kb + k2;
      float fv = flds[row][k];
      f32x4 wv = *(const f32x4*)&wlds[k][eg * 4];
      acc0 += fv * wv[0]; acc1 += fv * wv[1]; acc2 += fv * wv[2]; acc3 += fv * wv[3];
    }
  }
  red[wave][lane][0] = acc0; red[wave][lane][1] = acc1;
  red[wave][lane][2] = acc2; red[wave][lane][3] = acc3;
  __syncthreads();
  if (t < 64) {
    f32x4 s = *(f32x4*)&red[0][t][0];
    #pragma unroll
    for (int w2 = 1; w2 < 4; ++w2) {
      f32x4 v = *(f32x4*)&red[w2][t][0];
      s[0] += v[0]; s[1] += v[1]; s[2] += v[2]; s[3] += v[3];
    }
    int r = rowBase + (t >> 3);
    int e0 = (t & 7) * 4;
    #pragma unroll
    for (int q = 0; q < 4; ++q) {
      int e = e0 + q;
      if (e < 16) att_l[(size_t)r * 16 + e]        = s[q] + bl[e];
      else        att_r[(size_t)r * 16 + (e - 16)] = s[q] + br[e - 16];
    }
  }
}

// ---------------- K3: edge scores + BN + softmax ----------------
__global__ __launch_bounds__(256) void k_edge(const float* __restrict__ att_l,
    const float* __restrict__ att_r, const float* __restrict__ gamma,
    const float* __restrict__ beta, float* __restrict__ w_t) {
  __shared__ __align__(16) float attr[BB][20];
  __shared__ float el[NN][BB + 1];
  __shared__ float part[NN][4][2];
  __shared__ float sc[NN], sh[NN];
  int d = blockIdx.x, t = threadIdx.x;
  for (int i = t; i < 512; i += 256) {
    int b = i >> 2, e = (i & 3) * 4;
    *(f32x4*)&attr[b][e] = *(const f32x4*)&att_r[((size_t)d * BB + b) * 16 + e];
  }
  __syncthreads();
  for (int v = t; v < NN * BB; v += 256) {
    int s = v >> 7, b = v & 127;
    const float* al = &att_l[((size_t)s * BB + b) * 16];
    float acc = 0.f;
    #pragma unroll
    for (int e4 = 0; e4 < 4; ++e4) {
      f32x4 a = *(const f32x4*)&al[e4 * 4];
      f32x4 r = *(const f32x4*)&attr[b][e4 * 4];
      acc += a[0] * r[0] + a[1] * r[1] + a[2] * r[2] + a[3] * r[3];
    }
    el[s][b] = acc;
  }
  __syncthreads();
  {
    int s = t >> 2, q = t & 3;
    float sum = 0.f, ss = 0.f;
    for (int b = q * 32; b < q * 32 + 32; ++b) { float x = el[s][b]; sum += x; ss += x * x; }
    part[s][q][0] = sum; part[s][q][1] = ss;
  }
  __syncthreads();
  if (t < 64) {
    float sum = 0.f, ss = 0.f;
    #pragma unroll
    for (int q = 0; q < 4; ++q) { sum += part[t][q][0]; ss += part[t][q][1]; }
    float mu = sum * (1.f / 128.f);
    float var = ss * (1.f / 128.f) - mu * mu;
    int c = d * 64 + t;
    float a = gamma[c] * rsqrtf(fmaxf(var, 0.f) + 1e-5f);
    sc[t] = a; sh[t] = beta[c] - mu * a;
  }
  __syncthreads();
  if (t < 128) {
    int b = t;
    float y[64];
    float m = -1e30f;
    #pragma unroll
    for (int s = 0; s < 64; ++s) { y[s] = sc[s] * el[s][b] + sh[s]; m = fmaxf(m, y[s]); }
    float sum = 0.f;
    #pragma unroll
    for (int s = 0; s < 64; ++s) { y[s] = __expf(y[s] - m); sum += y[s]; }
    float inv = 1.f / sum;
    float* wp = &w_t[((size_t)b * 64 + d) * 64];
    #pragma unroll
    for (int s4 = 0; s4 < 16; ++s4) {
      f32x4 o;
      o[0] = y[s4 * 4 + 0] * inv; o[1] = y[s4 * 4 + 1] * inv;
      o[2] = y[s4 * 4 + 2] * inv; o[3] = y[s4 * 4 + 3] * inv;
      *(f32x4*)&wp[s4 * 4] = o;
    }
  }
}

// ---------------- K4: 256x256 8-phase bf16 MFMA GEMM ----------------
// out = relu(feat_bf @ wm_bf^T + bm). BM=BN=256, BK=64, 8 waves (2M x 4N),
// LDS 128KB (2 dbuf x [A,B] x [k-half0,k-half1] of 256x32 bf16, st_16x32 swizzle).
// Half-ring consumption order per tile: [A-k0, B-k0, A-k1, B-k1]; staging runs
// 7 halves ahead; counted vmcnt(6) at tile boundary only (never 0 in main loop).
#define LDS_A 0
#define LDS_B 65536
#define BAR   do { __builtin_amdgcn_sched_barrier(0); __builtin_amdgcn_s_barrier(); __builtin_amdgcn_sched_barrier(0); } while (0)
#define LGKM0 do { asm volatile("s_waitcnt lgkmcnt(0)" ::: "memory"); __builtin_amdgcn_sched_barrier(0); } while (0)
#define VM6   asm volatile("s_waitcnt vmcnt(6)" ::: "memory")
#define VM4   asm volatile("s_waitcnt vmcnt(4)" ::: "memory")
#define VM0   asm volatile("s_waitcnt vmcnt(0)" ::: "memory")
#define PRIO1 __builtin_amdgcn_s_setprio(1)
#define PRIO0 __builtin_amdgcn_s_setprio(0)
#define MFMA(a, b, c) __builtin_amdgcn_mfma_f32_16x16x32_bf16((a), (b), (c), 0, 0, 0)
#define STAGE2(g0, g1, ldsoff) do { \
    gload16((g0), lds_raw + (ldsoff) + tid16); \
    gload16((g1), lds_raw + (ldsoff) + 8192 + tid16); } while (0)

__global__ __launch_bounds__(512, 2) void k_gemm8(const unsigned short* __restrict__ A,
    const unsigned short* __restrict__ Bm, const float* __restrict__ bm,
    unsigned short* __restrict__ C) {
  __shared__ __align__(16) char lds_raw[131072];
  const int tid = threadIdx.x;
  const int lane = tid & 63, wave = tid >> 6;
  const int wm = wave >> 2, wn = wave & 3;
  // XCD-aware bijective swizzle (512 wgs % 8 == 0)
  int bid = blockIdx.x;
  int swz = (bid & 7) * 64 + (bid >> 3);
  int tM = swz >> 4, tN = swz & 15;
  const size_t rowBase = (size_t)tM * 256, colBase = (size_t)tN * 256;
  // staging source decode (inverse st_16x32 swizzle; LDS dest is linear)
  const int tid16 = tid * 16;
  const int o0 = tid16, o1 = tid16 + 8192;
  const int r0s = (o0 & 1023) >> 6, r1s = (o1 & 1023) >> 6;
  const int row0 = (o0 >> 10) * 16 + r0s, row1 = (o1 >> 10) * 16 + r1s;
  const int col0 = (((o0 >> 4) & 3) ^ ((r0s >> 3) << 1)) * 8;
  const int col1 = (((o1 >> 4) & 3) ^ ((r1s >> 3) << 1)) * 8;
  const unsigned short* aR0 = A  + (rowBase + row0) * LL + col0;
  const unsigned short* aR1 = A  + (rowBase + row1) * LL + col1;
  const unsigned short* bR0 = Bm + (colBase + row0) * LL + col0;
  const unsigned short* bR1 = Bm + (colBase + row1) * LL + col1;
  // ds_read swizzled lane base
  const int rr = lane & 15, gg = lane >> 4;
  const int rdswz = rr * 64 + ((gg ^ ((rr >> 3) << 1)) << 4);
  f32x4 acc[8][4] = {};
  // ---- prologue: stage halves s0..s6 ----
  STAGE2(aR0 +  0, aR1 +  0, LDS_A + 0);            // t0 A-k0
  STAGE2(bR0 +  0, bR1 +  0, LDS_B + 0);            // t0 B-k0
  STAGE2(aR0 + 32, aR1 + 32, LDS_A + 16384);        // t0 A-k1
  STAGE2(bR0 + 32, bR1 + 32, LDS_B + 16384);        // t0 B-k1
  VM4;
  STAGE2(aR0 + 64, aR1 + 64, LDS_A + 32768);        // t1 A-k0
  STAGE2(bR0 + 64, bR1 + 64, LDS_B + 32768);        // t1 B-k0
  STAGE2(aR0 + 96, aR1 + 96, LDS_A + 32768 + 16384);// t1 A-k1
  VM6;
  BAR;
  #pragma unroll 2
  for (int t = 0; t < 64; ++t) {
    const int d = t & 1;
    const char* pA = lds_raw + LDS_A + d * 32768 + wm * 8192 + rdswz;
    const char* pB = lds_raw + LDS_B + d * 32768 + wn * 4096 + rdswz;
    short8 ar[8], bx, by;
    // ---- phase 0: read A-k0 (8) + B-k0 nj{0,1} (2); stage t+1 B-k1 ----
    #pragma unroll
    for (int mi = 0; mi < 8; ++mi) ar[mi] = *(const short8*)(pA + mi * 1024);
    bx = *(const short8*)(pB + 0);
    by = *(const short8*)(pB + 1024);
    if (t <= 62) { size_t kc = (size_t)(t + 1) * 64 + 32;
      STAGE2(bR0 + kc, bR1 + kc, LDS_B + ((t + 1) & 1) * 32768 + 16384); }
    BAR; LGKM0; PRIO1;
    #pragma unroll
    for (int mi = 0; mi < 8; ++mi) {
      acc[mi][0] = MFMA(ar[mi], bx, acc[mi][0]);
      acc[mi][1] = MFMA(ar[mi], by, acc[mi][1]);
    }
    PRIO0; BAR;
    // ---- phase 1: read B-k0 nj{2,3}; stage t+2 A-k0 ----
    bx = *(const short8*)(pB + 2048);
    by = *(const short8*)(pB + 3072);
    if (t <= 61) { size_t kc = (size_t)(t + 2) * 64;
      STAGE2(aR0 + kc, aR1 + kc, LDS_A + d * 32768); }
    BAR; LGKM0; PRIO1;
    #pragma unroll
    for (int mi = 0; mi < 8; ++mi) {
      acc[mi][2] = MFMA(ar[mi], bx, acc[mi][2]);
      acc[mi][3] = MFMA(ar[mi], by, acc[mi][3]);
    }
    PRIO0; BAR;
    // ---- phase 2: read A-k1 (8) + B-k1 nj{2,3}; stage t+2 B-k0 ----
    #pragma unroll
    for (int mi = 0; mi < 8; ++mi) ar[mi] = *(const short8*)(pA + 16384 + mi * 1024);
    bx = *(const short8*)(pB + 16384 + 2048);
    by = *(const short8*)(pB + 16384 + 3072);
    if (t <= 61) { size_t kc = (size_t)(t + 2) * 64;
      STAGE2(bR0 + kc, bR1 + kc, LDS_B + d * 32768); }
    BAR; LGKM0; PRIO1;
    #pragma unroll
    for (int mi = 0; mi < 8; ++mi) {
      acc[mi][2] = MFMA(ar[mi], bx, acc[mi][2]);
      acc[mi][3] = MFMA(ar[mi], by, acc[mi][3]);
    }
    PRIO0; BAR;
    // ---- phase 3: read B-k1 nj{0,1}; stage t+2 A-k1; boundary vmcnt ----
    bx = *(const short8*)(pB + 16384);
    by = *(const short8*)(pB + 16384 + 1024);
    if (t <= 61) { size_t kc = (size_t)(t + 2) * 64 + 32;
      STAGE2(aR0 + kc, aR1 + kc, LDS_A + d * 32768 + 16384); }
    BAR; LGKM0; PRIO1;
    #pragma unroll
    for (int mi = 0; mi < 8; ++mi) {
      acc[mi][0] = MFMA(ar[mi], bx, acc[mi][0]);
      acc[mi][1] = MFMA(ar[mi], by, acc[mi][1]);
    }
    PRIO0;
    if (t < 62) { VM6; } else { VM0; }
    BAR;
  }
  // ---- epilogue: +bm, ReLU, bf16 store ----
  const int co = lane & 15, ro4 = (lane >> 4) * 4;
  #pragma unroll
  for (int mig = 0; mig < 8; ++mig) {
    size_t r0 = rowBase + (size_t)wm * 128 + mig * 16 + ro4;
    #pragma unroll
    for (int nj = 0; nj < 4; ++nj) {
      size_t c = colBase + (size_t)wn * 64 + nj * 16 + co;
      float bc = bm[c];
      #pragma unroll
      for (int j = 0; j < 4; ++j) {
        float v = acc[mig][nj][j] + bc;
        v = fmaxf(v, 0.f);
        C[(r0 + j) * LL + c] = f2bf(v);
      }
    }
  }
}

// ---------------- K5: rst[d,b,l] = sum_s w[d,s,b]*out[s,b,l] + bias[l] ----------------
__global__ __launch_bounds__(256) void k_agg(const float* __restrict__ w_t,
    const unsigned short* __restrict__ outb, const float* __restrict__ bias,
    float* __restrict__ rst) {
  __shared__ __align__(16) float wl[64][64];
  int b = blockIdx.y;
  int t = threadIdx.x;
  int l = blockIdx.x * 256 + t;
  {
    const f32x4* src = (const f32x4*)&w_t[(size_t)b * 4096];
    f32x4* dstp = (f32x4*)&wl[0][0];
    for (int i = t; i < 1024; i += 256) dstp[i] = src[i];
  }
  __syncthreads();
  float o[64];
  #pragma unroll
  for (int s = 0; s < 64; ++s) o[s] = bf2f(outb[((size_t)s * BB + b) * LL + l]);
  float bs = bias[l];
  #pragma unroll 2
  for (int d = 0; d < 64; ++d) {
    float acc = 0.f;
    #pragma unroll
    for (int s4 = 0; s4 < 16; ++s4) {
      f32x4 wv = *(const f32x4*)&wl[d][s4 * 4];
      acc += wv[0] * o[s4 * 4 + 0] + wv[1] * o[s4 * 4 + 1]
           + wv[2] * o[s4 * 4 + 2] + wv[3] * o[s4 * 4 + 3];
    }
    rst[((size_t)d * BB + b) * LL + l] = acc + bs;
  }
}

extern "C" void kernel_launch(void* const* d_in, const int* in_sizes, int n_in,
                              void* d_out, int out_size, void* d_ws, size_t ws_size,
                              hipStream_t stream) {
  (void)in_sizes; (void)n_in; (void)out_size; (void)ws_size;
  const float* feat  = (const float*)d_in[0];
  const float* Wl    = (const float*)d_in[1];
  const float* bl    = (const float*)d_in[2];
  const float* Wr    = (const float*)d_in[3];
  const float* br    = (const float*)d_in[4];
  const float* Wm    = (const float*)d_in[5];
  const float* bm    = (const float*)d_in[6];
  const float* gamma = (const float*)d_in[7];
  const float* beta  = (const float*)d_in[8];
  const float* bias  = (const float*)d_in[9];
  char* ws = (char*)d_ws;
  unsigned short* feat_bf = (unsigned short*)(ws);                 // 67,108,864
  unsigned short* wm_bf   = (unsigned short*)(ws + 67108864ull);   // 33,554,432
  unsigned short* out_bf  = (unsigned short*)(ws + 100663296ull);  // 67,108,864
  float* att_l = (float*)(ws + 167772160ull);
  float* att_r = (float*)(ws + 168296448ull);
  float* w_t   = (float*)(ws + 168820736ull);
  float* rst = (float*)d_out;

  k_cvt<<<dim3(2048), dim3(256), 0, stream>>>(Wm, wm_bf, (LL * LL) / 4);
  k_att<<<dim3(1024), dim3(256), 0, stream>>>(feat, Wl, bl, Wr, br, feat_bf, att_l, att_r);
  k_edge<<<dim3(64), dim3(256), 0, stream>>>(att_l, att_r, gamma, beta, w_t);
  k_gemm8<<<dim3(512), dim3(512), 0, stream>>>(feat_bf, wm_bf, bm, out_bf);
  k_agg<<<dim3(16, 128), dim3(256), 0, stream>>>(w_t, out_bf, bias, rst);
}